// Round 2
// baseline (725.741 us; speedup 1.0000x reference)
//
#include <hip/hip_runtime.h>
#include <math.h>

// CapsNet dynamic routing, LDS-free data path.
// lane = b (64 b / block), wave = c-pair (5 waves = 10 digit caps).
// w reads wave-uniform (scalar-address broadcast), x reads per-lane, softmax in-register,
// only the 10 logits cross waves via a 5KB LDS exchange (1 barrier per n).
//   x: [512,1152,8] f32, w: [10,1152,16,8] f32, out: [512,10,16] f32

#define BB   512
#define NN1  1152
#define DD1  8
#define CC2  10
#define DD2  16
#define CD   160            // CC2*DD2
#define WCN  (NN1*DD2*DD1)  // 147456 floats per c in w
#define XB   (NN1*DD1)      // 9216 floats per b in x
#define BT   64             // b per block (one per lane)
#define NBC  (BB/BT)        // 8 b-chunks
#define NSPLIT 64           // n-splits
#define NT   (NN1/NSPLIT)   // 18 n per block

// ---------------- P1: s0[b,c,d] = sum_n x_hat  (uniform c=0.1 folded into squash) ----------
__global__ __launch_bounds__(320) void caps_p1(
    const float* __restrict__ x, const float* __restrict__ w, float* __restrict__ s0)
{
    const int bc   = blockIdx.x >> 6;
    const int ns   = blockIdx.x & 63;
    const int lane = threadIdx.x & 63;
    const int b    = bc * BT + lane;
    const int q    = __builtin_amdgcn_readfirstlane((int)(threadIdx.x >> 6)); // wave 0..4
    const int c0   = 2 * q;
    const int n0   = ns * NT;

    const float* xrow = x + b * XB;
    const float* wc0  = w + c0 * WCN;
    const float* wc1  = wc0 + WCN;

    float a0[16], a1[16];
#pragma unroll
    for (int d = 0; d < 16; ++d) { a0[d] = 0.f; a1[d] = 0.f; }

    for (int t = 0; t < NT; ++t) {
        const int n = n0 + t;
        const float* xp = xrow + n * DD1;
        float4 xa = *(const float4*)(xp);
        float4 xb = *(const float4*)(xp + 4);
        const float* p0 = wc0 + n * 128;   // wave-uniform addresses
        const float* p1 = wc1 + n * 128;
#pragma unroll
        for (int d = 0; d < 16; ++d) {
            float4 wa = *(const float4*)(p0 + d * 8);
            float4 wb = *(const float4*)(p0 + d * 8 + 4);
            a0[d] += wa.x*xa.x + wa.y*xa.y + wa.z*xa.z + wa.w*xa.w
                   + wb.x*xb.x + wb.y*xb.y + wb.z*xb.z + wb.w*xb.w;
        }
#pragma unroll
        for (int d = 0; d < 16; ++d) {
            float4 wa = *(const float4*)(p1 + d * 8);
            float4 wb = *(const float4*)(p1 + d * 8 + 4);
            a1[d] += wa.x*xa.x + wa.y*xa.y + wa.z*xa.z + wa.w*xa.w
                   + wb.x*xb.x + wb.y*xb.y + wb.z*xb.z + wb.w*xb.w;
        }
    }

    float* o = s0 + b * CD + c0 * DD2;
#pragma unroll
    for (int d = 0; d < 16; ++d) atomicAdd(o + d, a0[d]);
#pragma unroll
    for (int d = 0; d < 16; ++d) atomicAdd(o + DD2 + d, a1[d]);
}

// ---------------- squash(0.1 * s0) in place -> o0 ----------------
__global__ void caps_squash_a(float* __restrict__ s)
{
    int t = blockIdx.x * blockDim.x + threadIdx.x;
    if (t >= BB * CC2) return;
    float* p = s + t * DD2;
    float4 v0 = *(float4*)(p), v1 = *(float4*)(p + 4), v2 = *(float4*)(p + 8), v3 = *(float4*)(p + 12);
    float ss = v0.x*v0.x + v0.y*v0.y + v0.z*v0.z + v0.w*v0.w
             + v1.x*v1.x + v1.y*v1.y + v1.z*v1.z + v1.w*v1.w
             + v2.x*v2.x + v2.y*v2.y + v2.z*v2.z + v2.w*v2.w
             + v3.x*v3.x + v3.y*v3.y + v3.z*v3.z + v3.w*v3.w;
    float sq = 0.01f * ss;                       // |0.1*raw|^2
    float sc = sq / (1.f + sq) / sqrtf(ss);      // 0.1/sqrt(sq) == 1/sqrt(ss)
    v0.x*=sc; v0.y*=sc; v0.z*=sc; v0.w*=sc; v1.x*=sc; v1.y*=sc; v1.z*=sc; v1.w*=sc;
    v2.x*=sc; v2.y*=sc; v2.z*=sc; v2.w*=sc; v3.x*=sc; v3.y*=sc; v3.z*=sc; v3.w*=sc;
    *(float4*)(p) = v0; *(float4*)(p + 4) = v1; *(float4*)(p + 8) = v2; *(float4*)(p + 12) = v3;
}

// ---------------- P2: logits + softmax + weighted sum, fused, LDS only for logit exchange ----
__global__ __launch_bounds__(320) void caps_p2(
    const float* __restrict__ x, const float* __restrict__ w,
    const float* __restrict__ o0, float* __restrict__ out)
{
    __shared__ float sl[2][CC2][BT];   // 5120 B logit exchange, double-buffered

    const int bc   = blockIdx.x >> 6;
    const int ns   = blockIdx.x & 63;
    const int lane = threadIdx.x & 63;
    const int b    = bc * BT + lane;
    const int q    = __builtin_amdgcn_readfirstlane((int)(threadIdx.x >> 6));
    const int c0   = 2 * q;
    const int n0   = ns * NT;

    const float* xrow = x + b * XB;
    const float* wc0  = w + c0 * WCN;
    const float* wc1  = wc0 + WCN;

    float o0r[2][16];
    {
        const float* p = o0 + b * CD + c0 * DD2;
#pragma unroll
        for (int h = 0; h < 2; ++h) {
            float4 u0 = *(const float4*)(p + h * DD2);
            float4 u1 = *(const float4*)(p + h * DD2 + 4);
            float4 u2 = *(const float4*)(p + h * DD2 + 8);
            float4 u3 = *(const float4*)(p + h * DD2 + 12);
            o0r[h][0]=u0.x;  o0r[h][1]=u0.y;  o0r[h][2]=u0.z;  o0r[h][3]=u0.w;
            o0r[h][4]=u1.x;  o0r[h][5]=u1.y;  o0r[h][6]=u1.z;  o0r[h][7]=u1.w;
            o0r[h][8]=u2.x;  o0r[h][9]=u2.y;  o0r[h][10]=u2.z; o0r[h][11]=u2.w;
            o0r[h][12]=u3.x; o0r[h][13]=u3.y; o0r[h][14]=u3.z; o0r[h][15]=u3.w;
        }
    }

    float s1a[2][16];
#pragma unroll
    for (int d = 0; d < 16; ++d) { s1a[0][d] = 0.f; s1a[1][d] = 0.f; }

    for (int t = 0; t < NT; ++t) {
        const int n = n0 + t;
        const float* xp = xrow + n * DD1;
        float4 xa = *(const float4*)(xp);
        float4 xb = *(const float4*)(xp + 4);
        const float* p0 = wc0 + n * 128;
        const float* p1 = wc1 + n * 128;

        float xh0[16], xh1[16];
#pragma unroll
        for (int d = 0; d < 16; ++d) {
            float4 wa = *(const float4*)(p0 + d * 8);
            float4 wb = *(const float4*)(p0 + d * 8 + 4);
            xh0[d] = wa.x*xa.x + wa.y*xa.y + wa.z*xa.z + wa.w*xa.w
                   + wb.x*xb.x + wb.y*xb.y + wb.z*xb.z + wb.w*xb.w;
        }
#pragma unroll
        for (int d = 0; d < 16; ++d) {
            float4 wa = *(const float4*)(p1 + d * 8);
            float4 wb = *(const float4*)(p1 + d * 8 + 4);
            xh1[d] = wa.x*xa.x + wa.y*xa.y + wa.z*xa.z + wa.w*xa.w
                   + wb.x*xb.x + wb.y*xb.y + wb.z*xb.z + wb.w*xb.w;
        }
        float l0 = 0.f, l1 = 0.f;
#pragma unroll
        for (int d = 0; d < 16; ++d) { l0 += o0r[0][d] * xh0[d]; l1 += o0r[1][d] * xh1[d]; }

        sl[t & 1][c0][lane]     = l0;
        sl[t & 1][c0 + 1][lane] = l1;
        __syncthreads();
        // next iter writes the OTHER buffer; barrier t+1 orders re-write of this one. Safe.

        float lv[10];
#pragma unroll
        for (int j = 0; j < 10; ++j) lv[j] = sl[t & 1][j][lane];
        float m = lv[0];
#pragma unroll
        for (int j = 1; j < 10; ++j) m = fmaxf(m, lv[j]);
        float den = 0.f;
#pragma unroll
        for (int j = 0; j < 10; ++j) den += __expf(lv[j] - m);
        float inv = 1.f / den;
        float w0 = __expf(lv[c0] - m) * inv;
        float w1 = __expf(lv[c0 + 1] - m) * inv;
#pragma unroll
        for (int d = 0; d < 16; ++d) { s1a[0][d] += w0 * xh0[d]; s1a[1][d] += w1 * xh1[d]; }
    }

    float* o = out + b * CD + c0 * DD2;
#pragma unroll
    for (int d = 0; d < 16; ++d) atomicAdd(o + d, s1a[0][d]);
#pragma unroll
    for (int d = 0; d < 16; ++d) atomicAdd(o + DD2 + d, s1a[1][d]);
}

// ---------------- final squash(s1) in place on d_out ----------------
__global__ void caps_squash_b(float* __restrict__ s)
{
    int t = blockIdx.x * blockDim.x + threadIdx.x;
    if (t >= BB * CC2) return;
    float* p = s + t * DD2;
    float4 v0 = *(float4*)(p), v1 = *(float4*)(p + 4), v2 = *(float4*)(p + 8), v3 = *(float4*)(p + 12);
    float ss = v0.x*v0.x + v0.y*v0.y + v0.z*v0.z + v0.w*v0.w
             + v1.x*v1.x + v1.y*v1.y + v1.z*v1.z + v1.w*v1.w
             + v2.x*v2.x + v2.y*v2.y + v2.z*v2.z + v2.w*v2.w
             + v3.x*v3.x + v3.y*v3.y + v3.z*v3.z + v3.w*v3.w;
    float sc = ss / (1.f + ss) / sqrtf(ss);
    v0.x*=sc; v0.y*=sc; v0.z*=sc; v0.w*=sc; v1.x*=sc; v1.y*=sc; v1.z*=sc; v1.w*=sc;
    v2.x*=sc; v2.y*=sc; v2.z*=sc; v2.w*=sc; v3.x*=sc; v3.y*=sc; v3.z*=sc; v3.w*=sc;
    *(float4*)(p) = v0; *(float4*)(p + 4) = v1; *(float4*)(p + 8) = v2; *(float4*)(p + 12) = v3;
}

extern "C" void kernel_launch(void* const* d_in, const int* in_sizes, int n_in,
                              void* d_out, int out_size, void* d_ws, size_t ws_size,
                              hipStream_t stream)
{
    (void)in_sizes; (void)n_in; (void)out_size; (void)ws_size;
    const float* x = (const float*)d_in[0];
    const float* w = (const float*)d_in[1];
    float* out = (float*)d_out;
    float* s0  = (float*)d_ws;            // 81920 floats; squashed in place -> o0

    hipMemsetAsync(s0, 0, BB * CD * sizeof(float), stream);
    hipMemsetAsync(out, 0, BB * CD * sizeof(float), stream);

    caps_p1      <<<NBC * NSPLIT, 320, 0, stream>>>(x, w, s0);
    caps_squash_a<<<(BB * CC2 + 255) / 256, 256, 0, stream>>>(s0);
    caps_p2      <<<NBC * NSPLIT, 320, 0, stream>>>(x, w, s0, out);
    caps_squash_b<<<(BB * CC2 + 255) / 256, 256, 0, stream>>>(out);
}

// Round 3
// 251.274 us; speedup vs baseline: 2.8882x; 2.8882x over previous
//
#include <hip/hip_runtime.h>
#include <math.h>

// CapsNet dynamic routing. lane = b (64/block), wave = c-pair (5 waves = 10 caps).
// w reads wave-uniform broadcast loads, x per-lane, softmax in-register, logits cross
// waves via 5KB LDS (1 barrier/n). NO atomics: per-block partials -> plain stores into
// ws slab P[ns][b][160], reduced+squashed by a small second kernel (LLC-resident).
//   x: [512,1152,8] f32, w: [10,1152,16,8] f32, out: [512,10,16] f32

#define BB   512
#define NN1  1152
#define DD1  8
#define CC2  10
#define DD2  16
#define CD   160            // CC2*DD2
#define WCN  (NN1*DD2*DD1)  // 147456 floats per c in w
#define XB   (NN1*DD1)      // 9216 floats per b in x
#define BT   64             // b per block (one per lane)
#define NBC  (BB/BT)        // 8 b-chunks

// ---------------- P1: partial s0 over this block's n-slice (uniform c folded later) -------
template<int NS>
__global__ __launch_bounds__(320) void caps_p1(
    const float* __restrict__ x, const float* __restrict__ w, float* __restrict__ P)
{
    constexpr int NT = NN1 / NS;
    const int ns   = blockIdx.x;
    const int bc   = blockIdx.y;
    const int lane = threadIdx.x & 63;
    const int q    = __builtin_amdgcn_readfirstlane((int)(threadIdx.x >> 6)); // 0..4
    const int c0   = 2 * q;
    const int b    = bc * BT + lane;

    const float* xp = x + b * XB + ns * NT * DD1;
    const float* p0 = w + c0 * WCN + ns * NT * 128;
    const float* p1 = p0 + WCN;

    float a0[16], a1[16];
#pragma unroll
    for (int d = 0; d < 16; ++d) { a0[d] = 0.f; a1[d] = 0.f; }

    for (int t = 0; t < NT; ++t) {
        float4 xa = *(const float4*)(xp + t * DD1);
        float4 xb = *(const float4*)(xp + t * DD1 + 4);
#pragma unroll
        for (int d = 0; d < 16; ++d) {
            float4 wa = *(const float4*)(p0 + t * 128 + d * 8);
            float4 wb = *(const float4*)(p0 + t * 128 + d * 8 + 4);
            a0[d] += wa.x*xa.x + wa.y*xa.y + wa.z*xa.z + wa.w*xa.w
                   + wb.x*xb.x + wb.y*xb.y + wb.z*xb.z + wb.w*xb.w;
        }
#pragma unroll
        for (int d = 0; d < 16; ++d) {
            float4 wa = *(const float4*)(p1 + t * 128 + d * 8);
            float4 wb = *(const float4*)(p1 + t * 128 + d * 8 + 4);
            a1[d] += wa.x*xa.x + wa.y*xa.y + wa.z*xa.z + wa.w*xa.w
                   + wb.x*xb.x + wb.y*xb.y + wb.z*xb.z + wb.w*xb.w;
        }
    }

    float* o = P + ((size_t)ns * BB + b) * CD + c0 * DD2;
    *(float4*)(o)      = *(float4*)&a0[0];
    *(float4*)(o + 4)  = *(float4*)&a0[4];
    *(float4*)(o + 8)  = *(float4*)&a0[8];
    *(float4*)(o + 12) = *(float4*)&a0[12];
    *(float4*)(o + 16) = *(float4*)&a1[0];
    *(float4*)(o + 20) = *(float4*)&a1[4];
    *(float4*)(o + 24) = *(float4*)&a1[8];
    *(float4*)(o + 28) = *(float4*)&a1[12];
}

// ---------------- reduce over ns + squash(alpha * S); alpha^2 passed as asq -------------
__global__ void reduce_squash(const float* __restrict__ P, float* __restrict__ out,
                              int nsplit, float asq)
{
    int t = blockIdx.x * blockDim.x + threadIdx.x;   // (b,c): 5120 threads
    if (t >= BB * CC2) return;
    float4 s0 = {0,0,0,0}, s1 = {0,0,0,0}, s2 = {0,0,0,0}, s3 = {0,0,0,0};
    const float* p = P + t * DD2;
    for (int ns = 0; ns < nsplit; ++ns, p += (size_t)BB * CD) {
        float4 v0 = *(const float4*)(p);
        float4 v1 = *(const float4*)(p + 4);
        float4 v2 = *(const float4*)(p + 8);
        float4 v3 = *(const float4*)(p + 12);
        s0.x+=v0.x; s0.y+=v0.y; s0.z+=v0.z; s0.w+=v0.w;
        s1.x+=v1.x; s1.y+=v1.y; s1.z+=v1.z; s1.w+=v1.w;
        s2.x+=v2.x; s2.y+=v2.y; s2.z+=v2.z; s2.w+=v2.w;
        s3.x+=v3.x; s3.y+=v3.y; s3.z+=v3.z; s3.w+=v3.w;
    }
    float ss = s0.x*s0.x + s0.y*s0.y + s0.z*s0.z + s0.w*s0.w
             + s1.x*s1.x + s1.y*s1.y + s1.z*s1.z + s1.w*s1.w
             + s2.x*s2.x + s2.y*s2.y + s2.z*s2.z + s2.w*s2.w
             + s3.x*s3.x + s3.y*s3.y + s3.z*s3.z + s3.w*s3.w;
    float sq = asq * ss;                         // |alpha*S|^2
    float sc = sq / (1.f + sq) / sqrtf(ss);      // out = sc * S  (alpha folded)
    s0.x*=sc; s0.y*=sc; s0.z*=sc; s0.w*=sc; s1.x*=sc; s1.y*=sc; s1.z*=sc; s1.w*=sc;
    s2.x*=sc; s2.y*=sc; s2.z*=sc; s2.w*=sc; s3.x*=sc; s3.y*=sc; s3.z*=sc; s3.w*=sc;
    float* o = out + t * DD2;
    *(float4*)(o) = s0; *(float4*)(o + 4) = s1; *(float4*)(o + 8) = s2; *(float4*)(o + 12) = s3;
}

// ---------------- P2: logits + softmax + weighted sum; partials to P ---------------------
template<int NS>
__global__ __launch_bounds__(320) void caps_p2(
    const float* __restrict__ x, const float* __restrict__ w,
    const float* __restrict__ o0, float* __restrict__ P)
{
    constexpr int NT = NN1 / NS;
    __shared__ float sl[2][CC2][BT];   // logit exchange, double-buffered

    const int ns   = blockIdx.x;
    const int bc   = blockIdx.y;
    const int lane = threadIdx.x & 63;
    const int q    = __builtin_amdgcn_readfirstlane((int)(threadIdx.x >> 6));
    const int c0   = 2 * q;
    const int b    = bc * BT + lane;

    const float* xp = x + b * XB + ns * NT * DD1;
    const float* p0 = w + c0 * WCN + ns * NT * 128;
    const float* p1 = p0 + WCN;

    float o0r[2][16];
    {
        const float* p = o0 + b * CD + c0 * DD2;
#pragma unroll
        for (int h = 0; h < 2; ++h) {
            float4 u0 = *(const float4*)(p + h * DD2);
            float4 u1 = *(const float4*)(p + h * DD2 + 4);
            float4 u2 = *(const float4*)(p + h * DD2 + 8);
            float4 u3 = *(const float4*)(p + h * DD2 + 12);
            o0r[h][0]=u0.x;  o0r[h][1]=u0.y;  o0r[h][2]=u0.z;  o0r[h][3]=u0.w;
            o0r[h][4]=u1.x;  o0r[h][5]=u1.y;  o0r[h][6]=u1.z;  o0r[h][7]=u1.w;
            o0r[h][8]=u2.x;  o0r[h][9]=u2.y;  o0r[h][10]=u2.z; o0r[h][11]=u2.w;
            o0r[h][12]=u3.x; o0r[h][13]=u3.y; o0r[h][14]=u3.z; o0r[h][15]=u3.w;
        }
    }

    float s1a[2][16];
#pragma unroll
    for (int d = 0; d < 16; ++d) { s1a[0][d] = 0.f; s1a[1][d] = 0.f; }

    for (int t = 0; t < NT; ++t) {
        float4 xa = *(const float4*)(xp + t * DD1);
        float4 xb = *(const float4*)(xp + t * DD1 + 4);

        float xh0[16], xh1[16];
#pragma unroll
        for (int d = 0; d < 16; ++d) {
            float4 wa = *(const float4*)(p0 + t * 128 + d * 8);
            float4 wb = *(const float4*)(p0 + t * 128 + d * 8 + 4);
            xh0[d] = wa.x*xa.x + wa.y*xa.y + wa.z*xa.z + wa.w*xa.w
                   + wb.x*xb.x + wb.y*xb.y + wb.z*xb.z + wb.w*xb.w;
        }
#pragma unroll
        for (int d = 0; d < 16; ++d) {
            float4 wa = *(const float4*)(p1 + t * 128 + d * 8);
            float4 wb = *(const float4*)(p1 + t * 128 + d * 8 + 4);
            xh1[d] = wa.x*xa.x + wa.y*xa.y + wa.z*xa.z + wa.w*xa.w
                   + wb.x*xb.x + wb.y*xb.y + wb.z*xb.z + wb.w*xb.w;
        }
        float l0 = 0.f, l1 = 0.f;
#pragma unroll
        for (int d = 0; d < 16; ++d) { l0 += o0r[0][d] * xh0[d]; l1 += o0r[1][d] * xh1[d]; }

        sl[t & 1][c0][lane]     = l0;
        sl[t & 1][c0 + 1][lane] = l1;
        __syncthreads();   // write->read; double buffer keeps next write off this buffer

        float lv[10];
#pragma unroll
        for (int j = 0; j < 10; ++j) lv[j] = sl[t & 1][j][lane];
        float m = lv[0];
#pragma unroll
        for (int j = 1; j < 10; ++j) m = fmaxf(m, lv[j]);
        float den = 0.f;
#pragma unroll
        for (int j = 0; j < 10; ++j) den += __expf(lv[j] - m);
        float inv = 1.f / den;
        float w0 = __expf(lv[c0] - m) * inv;
        float w1 = __expf(lv[c0 + 1] - m) * inv;
#pragma unroll
        for (int d = 0; d < 16; ++d) { s1a[0][d] += w0 * xh0[d]; s1a[1][d] += w1 * xh1[d]; }
    }

    float* o = P + ((size_t)ns * BB + b) * CD + c0 * DD2;
    *(float4*)(o)      = *(float4*)&s1a[0][0];
    *(float4*)(o + 4)  = *(float4*)&s1a[0][4];
    *(float4*)(o + 8)  = *(float4*)&s1a[0][8];
    *(float4*)(o + 12) = *(float4*)&s1a[0][12];
    *(float4*)(o + 16) = *(float4*)&s1a[1][0];
    *(float4*)(o + 20) = *(float4*)&s1a[1][4];
    *(float4*)(o + 24) = *(float4*)&s1a[1][8];
    *(float4*)(o + 28) = *(float4*)&s1a[1][12];
}

extern "C" void kernel_launch(void* const* d_in, const int* in_sizes, int n_in,
                              void* d_out, int out_size, void* d_ws, size_t ws_size,
                              hipStream_t stream)
{
    (void)in_sizes; (void)n_in; (void)out_size;
    const float* x = (const float*)d_in[0];
    const float* w = (const float*)d_in[1];
    float* out = (float*)d_out;
    float* ws  = (float*)d_ws;

#define LAUNCH_NS(NS)                                                              \
    do {                                                                           \
        float* P  = ws;                                                            \
        float* o0 = ws + (size_t)(NS) * BB * CD;                                   \
        caps_p1<NS><<<dim3(NS, NBC), 320, 0, stream>>>(x, w, P);                   \
        reduce_squash<<<(BB*CC2 + 255)/256, 256, 0, stream>>>(P, o0, NS, 0.01f);   \
        caps_p2<NS><<<dim3(NS, NBC), 320, 0, stream>>>(x, w, o0, P);               \
        reduce_squash<<<(BB*CC2 + 255)/256, 256, 0, stream>>>(P, out, NS, 1.0f);   \
    } while (0)

    const size_t slab = (size_t)BB * CD * sizeof(float);   // 327680 B
    if      (ws_size >= slab * 129) LAUNCH_NS(128);
    else if (ws_size >= slab * 65)  LAUNCH_NS(64);
    else if (ws_size >= slab * 33)  LAUNCH_NS(32);
    else if (ws_size >= slab * 9)   LAUNCH_NS(8);
    else                            LAUNCH_NS(1);
#undef LAUNCH_NS
}